// Round 1
// baseline (91.351 us; speedup 1.0000x reference)
//
#include <hip/hip_runtime.h>

// dw1[12][24] at out[0..288), dw2[24][24] at out[288..864),
// s0[B][12] at out[864 ...), s1[B][24] after s0.

typedef __bf16 bf16x8 __attribute__((ext_vector_type(8)));
typedef float  f32x4  __attribute__((ext_vector_type(4)));

constexpr int TPB  = 384;   // 6 waves
constexpr int TILE = 384;   // rows per K-tile
constexpr int APAD = 392;   // 384 + 8 bf16 pad -> row stride 784B (196 dwords, =4 mod 32 banks)

__global__ void zero_dw_kernel(float* out) {
    int t = threadIdx.x + blockIdx.x * blockDim.x;
    if (t < 864) out[t] = 0.0f;
}

__global__ __launch_bounds__(TPB, 3)
void bnesnn_kernel(const float* __restrict__ x1, const float* __restrict__ x2,
                   const float* __restrict__ W0, const float* __restrict__ W1,
                   const float* __restrict__ W2, float* __restrict__ out, int B)
{
    // A^T tile: rows 0..11 = s0, rows 12..35 = x2, rows 36..47 = zero pad
    __shared__ __attribute__((aligned(16))) __bf16 aT[48][APAD];
    // B^T tile: rows 0..23 = s1, rows 24..31 = zero pad
    __shared__ __attribute__((aligned(16))) __bf16 bT[32][APAD];
    __shared__ float W0T[12][12];   // W0T[j][k] = W0[k][j]
    __shared__ float W1T[24][12];
    __shared__ float W2T[24][24];

    const int tid = threadIdx.x;

    // Load W transposed into LDS (for generic fallback + diagonals)
    for (int i = tid; i < 144; i += TPB) W0T[i % 12][i / 12] = W0[i];
    for (int i = tid; i < 288; i += TPB) W1T[i % 24][i / 24] = W1[i];
    for (int i = tid; i < 576; i += TPB) W2T[i % 24][i / 24] = W2[i];

    // Structure detection (uniform, deterministic): W0 diag, W1 zero, W2 diag
    bool ok = true;
    for (int i = tid; i < 144; i += TPB) { if ((i / 12) != (i % 12) && W0[i] != 0.0f) ok = false; }
    for (int i = tid; i < 288; i += TPB) { if (W1[i] != 0.0f) ok = false; }
    for (int i = tid; i < 576; i += TPB) { if ((i / 24) != (i % 24) && W2[i] != 0.0f) ok = false; }

    // Zero the pad rows once (never overwritten afterwards)
    for (int i = tid; i < 12 * APAD; i += TPB) aT[36 + i / APAD][i % APAD] = (__bf16)0.0f;
    for (int i = tid; i <  8 * APAD; i += TPB) bT[24 + i / APAD][i % APAD] = (__bf16)0.0f;

    const int fast = __syncthreads_and(ok ? 1 : 0);   // barrier + all-reduce

    float d0[12], d2[24];
    #pragma unroll
    for (int j = 0; j < 12; ++j) d0[j] = W0T[j][j];
    #pragma unroll
    for (int j = 0; j < 24; ++j) d2[j] = W2T[j][j];

    float* s0out = out + 864;
    float* s1out = out + 864 + (size_t)12 * B;

    const int l    = tid & 63;
    const int w    = tid >> 6;          // wave 0..5
    const int mt   = w % 3;             // m-tile 0..2 (m = 0..47)
    const int nt   = w / 3;             // n-tile 0..1 (n = 0..31)
    const int lrow = l & 15;
    const int kb   = (l >> 4) * 8;      // k sub-block within MFMA step

    f32x4 acc = {0.0f, 0.0f, 0.0f, 0.0f};

    const int NT = (B + TILE - 1) / TILE;
    for (int tile = blockIdx.x; tile < NT; tile += gridDim.x) {
        const int  r     = tile * TILE + tid;
        const bool valid = r < B;

        float x1v[12], x2v[24], s0v[12], s1v[24];
        if (valid) {
            const float4* p1 = (const float4*)(x1 + (size_t)r * 12);
            #pragma unroll
            for (int c = 0; c < 3; ++c) {
                float4 v = p1[c];
                x1v[4*c+0] = v.x; x1v[4*c+1] = v.y; x1v[4*c+2] = v.z; x1v[4*c+3] = v.w;
            }
            const float4* p2 = (const float4*)(x2 + (size_t)r * 24);
            #pragma unroll
            for (int c = 0; c < 6; ++c) {
                float4 v = p2[c];
                x2v[4*c+0] = v.x; x2v[4*c+1] = v.y; x2v[4*c+2] = v.z; x2v[4*c+3] = v.w;
            }
        } else {
            #pragma unroll
            for (int j = 0; j < 12; ++j) x1v[j] = 0.0f;
            #pragma unroll
            for (int j = 0; j < 24; ++j) x2v[j] = 0.0f;
        }

        if (fast) {
            // i0 = x1*diag(W0); i1 = x2*diag(W2) (W1==0). Exact match to ref for this data.
            #pragma unroll
            for (int j = 0; j < 12; ++j) s0v[j] = (x1v[j] * d0[j] > 0.5f) ? 1.0f : 0.0f;
            #pragma unroll
            for (int j = 0; j < 24; ++j) s1v[j] = (x2v[j] * d2[j] > 0.5f) ? 1.0f : 0.0f;
        } else {
            // Generic fp32 fallback
            #pragma unroll
            for (int j = 0; j < 12; ++j) {
                float a = 0.0f;
                #pragma unroll
                for (int k = 0; k < 12; ++k) a += x1v[k] * W0T[j][k];
                s0v[j] = (a > 0.5f) ? 1.0f : 0.0f;
            }
            #pragma unroll
            for (int j = 0; j < 24; ++j) {
                float a = 0.0f;
                #pragma unroll
                for (int k = 0; k < 12; ++k) a += s0v[k] * W1T[j][k];
                #pragma unroll
                for (int k = 0; k < 24; ++k) a += x2v[k] * W2T[j][k];
                s1v[j] = (a > 0.5f) ? 1.0f : 0.0f;
            }
        }

        if (valid) {
            float4* q0 = (float4*)(s0out + (size_t)r * 12);
            q0[0] = make_float4(s0v[0], s0v[1], s0v[2],  s0v[3]);
            q0[1] = make_float4(s0v[4], s0v[5], s0v[6],  s0v[7]);
            q0[2] = make_float4(s0v[8], s0v[9], s0v[10], s0v[11]);
            float4* q1 = (float4*)(s1out + (size_t)r * 24);
            #pragma unroll
            for (int c = 0; c < 6; ++c)
                q1[c] = make_float4(s1v[4*c+0], s1v[4*c+1], s1v[4*c+2], s1v[4*c+3]);
        }

        // Stage transposed bf16 tiles (invalid rows stage zeros)
        #pragma unroll
        for (int m = 0; m < 12; ++m) aT[m][tid]      = (__bf16)s0v[m];
        #pragma unroll
        for (int m = 0; m < 24; ++m) aT[12 + m][tid] = (__bf16)x2v[m];
        #pragma unroll
        for (int n = 0; n < 24; ++n) bT[n][tid]      = (__bf16)s1v[n];
        __syncthreads();

        // MFMA: D[m][n] += sum_k concat[k][m] * s1[k][n]
        const int arow = mt * 16 + lrow;
        const int brow = nt * 16 + lrow;
        #pragma unroll
        for (int kk = 0; kk < TILE; kk += 32) {
            bf16x8 af = *(const bf16x8*)&aT[arow][kk + kb];
            bf16x8 bf = *(const bf16x8*)&bT[brow][kk + kb];
            acc = __builtin_amdgcn_mfma_f32_16x16x32_bf16(af, bf, acc, 0, 0, 0);
        }
        __syncthreads();
    }

    // Epilogue: scatter accumulators (C/D layout: col = l&15, row = (l>>4)*4 + reg)
    #pragma unroll
    for (int i = 0; i < 4; ++i) {
        int m = mt * 16 + (l >> 4) * 4 + i;
        int n = nt * 16 + lrow;
        if (m < 36 && n < 24) {
            int addr = (m < 12) ? (m * 24 + n) : (288 + (m - 12) * 24 + n);
            atomicAdd(out + addr, acc[i]);
        }
    }
}

extern "C" void kernel_launch(void* const* d_in, const int* in_sizes, int n_in,
                              void* d_out, int out_size, void* d_ws, size_t ws_size,
                              hipStream_t stream) {
    const float* x1 = (const float*)d_in[0];
    const float* x2 = (const float*)d_in[1];
    const float* W0 = (const float*)d_in[2];
    const float* W1 = (const float*)d_in[3];
    const float* W2 = (const float*)d_in[4];
    float* out = (float*)d_out;
    const int B = in_sizes[0] / 12;
    if (B <= 0) return;

    zero_dw_kernel<<<dim3(4), dim3(256), 0, stream>>>(out);
    bnesnn_kernel<<<dim3(512), dim3(TPB), 0, stream>>>(x1, x2, W0, W1, W2, out, B);
}